// Round 2
// baseline (907.105 us; speedup 1.0000x reference)
//
#include <hip/hip_runtime.h>
#include <hip/hip_bf16.h>

// Problem constants: S=2048, B=32, He=Hd=1024, A=512, M = S*B = 65536.

typedef float f32x4 __attribute__((ext_vector_type(4)));
typedef __bf16 bf16x8 __attribute__((ext_vector_type(8)));

// workspace layout (bytes)
#define WS_DEC_OFF    0u                               // 32*512*4       = 65536
#define WS_WIMG_OFF   65536u                           // 32 chunks * 32KB = 1048576
#define WS_SCORES_OFF (65536u + 1048576u)              // 32*2048*4      = 262144
#define WS_PART_OFF   (65536u + 1048576u + 262144u)    // 16*32*1024*4   = 2097152

__device__ __forceinline__ void gload_lds16(const void* g, void* l) {
  __builtin_amdgcn_global_load_lds(
      (const __attribute__((address_space(1))) void*)g,
      (__attribute__((address_space(3))) void*)l, 16, 0, 0);
}

// ---------------------------------------------------------------------------
// dec_att[b][a] = dot(dec_out[b,:], W_dec[a,:])   (32 x 512, K=1024)
__global__ void dec_att_kernel(const float* __restrict__ dec_out,
                               const float* __restrict__ W_dec,
                               float* __restrict__ out) {
  int gtid = blockIdx.x * blockDim.x + threadIdx.x;
  int w = gtid >> 6;
  int lane = gtid & 63;
  int b = w >> 9;          // 0..31
  int a = w & 511;         // 0..511
  const float4* dp = (const float4*)(dec_out + b * 1024);
  const float4* wp = (const float4*)(W_dec + a * 1024);
  float sum = 0.f;
#pragma unroll
  for (int i = 0; i < 4; ++i) {
    float4 x = dp[lane + i * 64];
    float4 y = wp[lane + i * 64];
    sum += x.x * y.x + x.y * y.y + x.z * y.z + x.w * y.w;
  }
#pragma unroll
  for (int m = 32; m; m >>= 1) sum += __shfl_xor(sum, m, 64);
  if (lane == 0) out[b * 512 + a] = sum;
}

// ---------------------------------------------------------------------------
// Pre-convert W_enc (512x1024 f32) into 32 K-chunk images of layout
// [q=ksub 0..3][row 0..511][8 bf16]  (32 KB per chunk). This is exactly the
// conflict-free LDS image, so the GEMM stages B with pure global_load_lds.
// elem (kc,q,row,j) = W[row][kc*32 + q*8 + j]
__global__ void convert_wenc(const float* __restrict__ W, __bf16* __restrict__ out) {
  int idx = blockIdx.x * 256 + threadIdx.x;   // < 524288
  int kc = idx >> 14;
  int q = (idx >> 12) & 3;
  int row = (idx >> 3) & 511;
  int j = idx & 7;
  out[idx] = (__bf16)W[row * 1024 + kc * 32 + q * 8 + j];
}

// ---------------------------------------------------------------------------
// Main fused kernel: per 128-row tile of (S*B) compute full-width (A=512)
// enc_att via bf16 MFMA, then epilogue: scores = sum_a tanh(acc+dec_att)*att_v.
// 8 waves (2M x 4N), wave tile 64x128, 16x16x32 MFMA, K=1024 in BK=32 steps.
// Double-buffered A(2x8KB)+B(2x32KB) LDS, [q][row][16B] layout (bank-floor),
// stage(t+1) issued before MFMA(t), one barrier per K-step.
__global__ __launch_bounds__(512, 4) void scores_gemm(
    const float* __restrict__ enc,        // (65536, 1024) f32
    const __bf16* __restrict__ wimg,      // 32 chunks of [4][512][8] bf16
    const float* __restrict__ dec_att,    // [32][512] f32
    const float* __restrict__ attv,       // [512] f32
    float* __restrict__ scores) {         // [32][2048] f32
  __shared__ __align__(16) char smem[81920];   // A: [2][4][128][16B] @0, B: [2][4][512][16B] @16384
  float (*part)[4] = (float(*)[4])smem;        // reused (disjoint from live buffers at t=31)

  const int tid = threadIdx.x;
  const int lane = tid & 63;
  const int wid = tid >> 6;
  const int wr = wid >> 2;      // 0..1  (M half)
  const int wc = wid & 3;       // 0..3  (N quarter)
  const int q = lane >> 4;      // 0..3
  const int c0 = lane & 15;
  const int bm = blockIdx.x;    // 512 tiles

  f32x4 acc[4][8];
#pragma unroll
  for (int i = 0; i < 4; ++i)
#pragma unroll
    for (int j = 0; j < 8; ++j) acc[i][j] = (f32x4){0.f, 0.f, 0.f, 0.f};

  // A staging: thread stages row = tid>>2 (0..127), ksub = tid&3 (8 f32)
  const int srow = tid >> 2;
  const int sq = tid & 3;
  const float* asrc = enc + (size_t)(bm * 128 + srow) * 1024 + sq * 8;
  const char* bimg = (const char*)wimg;
  const int a_woff = sq * 2048 + srow * 16;          // ds_write offset within A buf

  // frag read offsets
  int a_roff[4], b_roff[8];
#pragma unroll
  for (int mf = 0; mf < 4; ++mf) a_roff[mf] = q * 2048 + (wr * 64 + mf * 16 + c0) * 16;
#pragma unroll
  for (int nf = 0; nf < 8; ++nf) b_roff[nf] = q * 8192 + (wc * 128 + nf * 16 + c0) * 16;

  // ---- prologue: stage tile 0 into buffer 0
  {
    const float4* as4 = (const float4*)asrc;
    float4 x = as4[0], y = as4[1];
#pragma unroll
    for (int p = 0; p < 4; ++p)
      gload_lds16(bimg + p * 8192 + tid * 16, smem + 16384 + p * 8192 + tid * 16);
    bf16x8 v;
    v[0] = (__bf16)x.x; v[1] = (__bf16)x.y; v[2] = (__bf16)x.z; v[3] = (__bf16)x.w;
    v[4] = (__bf16)y.x; v[5] = (__bf16)y.y; v[6] = (__bf16)y.z; v[7] = (__bf16)y.w;
    *(bf16x8*)(smem + a_woff) = v;
  }
  __syncthreads();

  // ---- main loop
  for (int t = 0; t < 32; ++t) {
    const int cur = t & 1;
    char* ab = smem + cur * 8192;
    char* bb = smem + 16384 + cur * 32768;
    float4 an0, an1;
    // issue next-tile stage (B direct-to-LDS, A global->reg)
    if (t < 31) {
      const char* bs = bimg + (size_t)(t + 1) * 32768;
      char* bd = smem + 16384 + (cur ^ 1) * 32768;
#pragma unroll
      for (int p = 0; p < 4; ++p)
        gload_lds16(bs + p * 8192 + tid * 16, bd + p * 8192 + tid * 16);
      const float4* as4 = (const float4*)(asrc + (t + 1) * 32);
      an0 = as4[0]; an1 = as4[1];
    }
    // fragments for tile t
    bf16x8 af[4], bfr[8];
#pragma unroll
    for (int mf = 0; mf < 4; ++mf) af[mf] = *(const bf16x8*)(ab + a_roff[mf]);
#pragma unroll
    for (int nf = 0; nf < 8; ++nf) bfr[nf] = *(const bf16x8*)(bb + b_roff[nf]);
    __builtin_amdgcn_s_setprio(1);
#pragma unroll
    for (int mf = 0; mf < 4; ++mf)
#pragma unroll
      for (int nf = 0; nf < 8; ++nf)
        acc[mf][nf] = __builtin_amdgcn_mfma_f32_16x16x32_bf16(af[mf], bfr[nf],
                                                              acc[mf][nf], 0, 0, 0);
    __builtin_amdgcn_s_setprio(0);
    // finish A stage for t+1 (cvt + ds_write into alt buffer)
    if (t < 31) {
      bf16x8 v;
      v[0] = (__bf16)an0.x; v[1] = (__bf16)an0.y; v[2] = (__bf16)an0.z; v[3] = (__bf16)an0.w;
      v[4] = (__bf16)an1.x; v[5] = (__bf16)an1.y; v[6] = (__bf16)an1.z; v[7] = (__bf16)an1.w;
      *(bf16x8*)(smem + (cur ^ 1) * 8192 + a_woff) = v;
    }
    __syncthreads();
  }

  // ---- epilogue: C/D layout col = lane&15, row = q*4 + reg
  float av[8];
#pragma unroll
  for (int nf = 0; nf < 8; ++nf) av[nf] = attv[wc * 128 + nf * 16 + c0];

#pragma unroll
  for (int mf = 0; mf < 4; ++mf) {
#pragma unroll
    for (int rg = 0; rg < 4; ++rg) {
      const int rl = wr * 64 + mf * 16 + q * 4 + rg;   // local row 0..127
      const int b = rl & 31;                           // r = s*32+b, tile%32==0
      const float* drow = dec_att + b * 512 + wc * 128 + c0;
      float sum = 0.f;
#pragma unroll
      for (int nf = 0; nf < 8; ++nf) {
        float x = acc[mf][nf][rg] + drow[nf * 16];
        float e = __expf(2.f * x);                     // tanh(x) = 1 - 2/(e^{2x}+1)
        float t = 1.f - 2.f / (e + 1.f);
        sum += t * av[nf];
      }
      sum += __shfl_xor(sum, 1, 64);
      sum += __shfl_xor(sum, 2, 64);
      sum += __shfl_xor(sum, 4, 64);
      sum += __shfl_xor(sum, 8, 64);
      if (c0 == 0) part[rl][wc] = sum;
    }
  }
  __syncthreads();
  if (tid < 128) {
    float tot = part[tid][0] + part[tid][1] + part[tid][2] + part[tid][3];
    int r = bm * 128 + tid;
    scores[(r & 31) * 2048 + (r >> 5)] = tot;          // scores[b][s]
  }
}

// ---------------------------------------------------------------------------
// softmax over S=2048 per batch row; 32 blocks x 256 threads
__global__ void softmax_kernel(const float* __restrict__ scores,
                               float* __restrict__ weights) {
  const int b = blockIdx.x;
  const int t = threadIdx.x;
  const float4* row = (const float4*)(scores + b * 2048);
  float4 v0 = row[t];
  float4 v1 = row[t + 256];
  float m = fmaxf(fmaxf(fmaxf(v0.x, v0.y), fmaxf(v0.z, v0.w)),
                  fmaxf(fmaxf(v1.x, v1.y), fmaxf(v1.z, v1.w)));
#pragma unroll
  for (int s = 32; s; s >>= 1) m = fmaxf(m, __shfl_xor(m, s, 64));
  __shared__ float redm[4], reds[4];
  if ((t & 63) == 0) redm[t >> 6] = m;
  __syncthreads();
  m = fmaxf(fmaxf(redm[0], redm[1]), fmaxf(redm[2], redm[3]));
  float4 e0, e1;
  e0.x = __expf(v0.x - m); e0.y = __expf(v0.y - m);
  e0.z = __expf(v0.z - m); e0.w = __expf(v0.w - m);
  e1.x = __expf(v1.x - m); e1.y = __expf(v1.y - m);
  e1.z = __expf(v1.z - m); e1.w = __expf(v1.w - m);
  float s8 = e0.x + e0.y + e0.z + e0.w + e1.x + e1.y + e1.z + e1.w;
#pragma unroll
  for (int s = 32; s; s >>= 1) s8 += __shfl_xor(s8, s, 64);
  if ((t & 63) == 0) reds[t >> 6] = s8;
  __syncthreads();
  float inv = 1.f / (reds[0] + reds[1] + reds[2] + reds[3]);
  e0.x *= inv; e0.y *= inv; e0.z *= inv; e0.w *= inv;
  e1.x *= inv; e1.y *= inv; e1.z *= inv; e1.w *= inv;
  float4* wrow = (float4*)(weights + b * 2048);
  wrow[t] = e0;
  wrow[t + 256] = e1;
}

// ---------------------------------------------------------------------------
// context partials: block = (b, h-chunk of 256, s-chunk of 128)
__global__ void ctx_partial(const float* __restrict__ enc,
                            const float* __restrict__ weights,
                            float* __restrict__ part) {
  const int bid = blockIdx.x;
  const int t = threadIdx.x;
  const int b = bid & 31;
  const int hc = (bid >> 5) & 3;
  const int sc = bid >> 7;          // 0..15
  const int h = hc * 256 + t;
  const float* wrow = weights + b * 2048 + sc * 128;
  const float* ebase = enc + ((size_t)(sc * 128) * 32 + b) * 1024 + h;
  float acc = 0.f;
#pragma unroll 4
  for (int i = 0; i < 128; ++i) acc += wrow[i] * ebase[(size_t)i * 32768];
  part[(size_t)(sc * 32 + b) * 1024 + h] = acc;
}

__global__ void ctx_reduce(const float* __restrict__ part, float* __restrict__ ctx) {
  int idx = blockIdx.x * 256 + threadIdx.x;   // < 32768
  float s = 0.f;
#pragma unroll
  for (int c = 0; c < 16; ++c) s += part[c * 32768 + idx];
  ctx[idx] = s;
}

// ---------------------------------------------------------------------------
extern "C" void kernel_launch(void* const* d_in, const int* in_sizes, int n_in,
                              void* d_out, int out_size, void* d_ws, size_t ws_size,
                              hipStream_t stream) {
  const float* dec_out  = (const float*)d_in[0];   // (32, 1024)
  const float* enc_outs = (const float*)d_in[1];   // (2048, 32, 1024)
  const float* W_enc    = (const float*)d_in[2];   // (512, 1024)
  const float* W_dec    = (const float*)d_in[3];   // (512, 1024)
  const float* att_v    = (const float*)d_in[4];   // (512,)

  float* out = (float*)d_out;
  float* ctx = out;                 // (32,1024) = 32768 floats
  float* weights = out + 32768;     // (32,2048) = 65536 floats

  char* ws = (char*)d_ws;
  float*  ws_dec    = (float*)(ws + WS_DEC_OFF);
  __bf16* ws_wimg   = (__bf16*)(ws + WS_WIMG_OFF);
  float*  ws_scores = (float*)(ws + WS_SCORES_OFF);
  float*  ws_part   = (float*)(ws + WS_PART_OFF);

  dec_att_kernel<<<4096, 256, 0, stream>>>(dec_out, W_dec, ws_dec);
  convert_wenc<<<2048, 256, 0, stream>>>(W_enc, ws_wimg);
  scores_gemm<<<512, 512, 0, stream>>>(enc_outs, ws_wimg, ws_dec, att_v, ws_scores);
  softmax_kernel<<<32, 256, 0, stream>>>(ws_scores, weights);
  ctx_partial<<<2048, 256, 0, stream>>>(enc_outs, weights, ws_part);
  ctx_reduce<<<128, 256, 0, stream>>>(ws_part, ctx);
}

// Round 3
// 159.281 us; speedup vs baseline: 5.6950x; 5.6950x over previous
//
#include <hip/hip_runtime.h>
#include <hip/hip_bf16.h>

// Problem constants: S=2048, B=32, He=Hd=1024, A=512, M = S*B = 65536.

typedef float f32x4 __attribute__((ext_vector_type(4)));
typedef __bf16 bf16x8 __attribute__((ext_vector_type(8)));

// workspace layout (bytes)
#define WS_DEC_OFF    0u                               // 32*512*4       = 65536
#define WS_WIMG_OFF   65536u                           // 32 chunks * 32KB = 1048576
#define WS_SCORES_OFF (65536u + 1048576u)              // 32*2048*4      = 262144
#define WS_PART_OFF   (65536u + 1048576u + 262144u)    // 16*32*1024*4   = 2097152

__device__ __forceinline__ void gload_lds16(const void* g, void* l) {
  __builtin_amdgcn_global_load_lds(
      (const __attribute__((address_space(1))) void*)g,
      (__attribute__((address_space(3))) void*)l, 16, 0, 0);
}

// ---------------------------------------------------------------------------
// dec_att[b][a] = dot(dec_out[b,:], W_dec[a,:])   (32 x 512, K=1024)
__global__ void dec_att_kernel(const float* __restrict__ dec_out,
                               const float* __restrict__ W_dec,
                               float* __restrict__ out) {
  int gtid = blockIdx.x * blockDim.x + threadIdx.x;
  int w = gtid >> 6;
  int lane = gtid & 63;
  int b = w >> 9;          // 0..31
  int a = w & 511;         // 0..511
  const float4* dp = (const float4*)(dec_out + b * 1024);
  const float4* wp = (const float4*)(W_dec + a * 1024);
  float sum = 0.f;
#pragma unroll
  for (int i = 0; i < 4; ++i) {
    float4 x = dp[lane + i * 64];
    float4 y = wp[lane + i * 64];
    sum += x.x * y.x + x.y * y.y + x.z * y.z + x.w * y.w;
  }
#pragma unroll
  for (int m = 32; m; m >>= 1) sum += __shfl_xor(sum, m, 64);
  if (lane == 0) out[b * 512 + a] = sum;
}

// ---------------------------------------------------------------------------
// Pre-convert W_enc (512x1024 f32) into 32 K-chunk images of layout
// [q=ksub 0..3][row 0..511][8 bf16]  (32 KB per chunk) == the conflict-free
// LDS image, so the GEMM stages B with pure global_load_lds.
// elem (kc,q,row,j) = W[row][kc*32 + q*8 + j]
__global__ void convert_wenc(const float* __restrict__ W, __bf16* __restrict__ out) {
  int idx = blockIdx.x * 256 + threadIdx.x;   // < 524288
  int kc = idx >> 14;
  int q = (idx >> 12) & 3;
  int row = (idx >> 3) & 511;
  int j = idx & 7;
  out[idx] = (__bf16)W[row * 1024 + kc * 32 + q * 8 + j];
}

// ---------------------------------------------------------------------------
// Main fused kernel: per 64-row tile of (S*B) compute full-width (A=512)
// enc_att via bf16 MFMA, epilogue scores = sum_a tanh(acc+dec_att)*att_v.
// 4 waves (1M x 4N), wave tile 64x128, 16x16x32 MFMA, K=1024 in BK=32 steps.
// Double-buffered A(2x4KB)+B(2x32KB) = 72KB LDS -> 2 blocks/CU at 256-reg cap.
// stage(t+1) issued before MFMA(t); A cvt+ds_write after MFMA; 1 barrier/step.
__global__ __launch_bounds__(256, 2) void scores_gemm(
    const float* __restrict__ enc,        // (65536, 1024) f32
    const __bf16* __restrict__ wimg,      // 32 chunks of [4][512][8] bf16
    const float* __restrict__ dec_att,    // [32][512] f32
    const float* __restrict__ attv,       // [512] f32
    float* __restrict__ scores) {         // [32][2048] f32
  // A: [2][4][64][16B] @0 (8KB), B: [2][4][512][16B] @8192 (64KB)
  __shared__ __align__(16) char smem[73728];
  float (*part)[4] = (float(*)[4])smem;   // reused after final barrier

  const int tid = threadIdx.x;
  const int lane = tid & 63;
  const int wc = tid >> 6;      // wave id 0..3 = N quarter
  const int q = lane >> 4;      // 0..3
  const int c0 = lane & 15;
  const int bm = blockIdx.x;    // 1024 tiles of 64 rows

  f32x4 acc[4][8];
#pragma unroll
  for (int i = 0; i < 4; ++i)
#pragma unroll
    for (int j = 0; j < 8; ++j) acc[i][j] = (f32x4){0.f, 0.f, 0.f, 0.f};

  // A staging: thread stages row = tid>>2 (0..63), ksub = tid&3 (8 f32)
  const int srow = tid >> 2;
  const int sq = tid & 3;
  const float* asrc = enc + (size_t)(bm * 64 + srow) * 1024 + sq * 8;
  const char* bimg = (const char*)wimg;
  const int a_woff = sq * 1024 + srow * 16;

  // ---- prologue: stage tile 0 into buffer 0
  {
    const float4* as4 = (const float4*)asrc;
    float4 x = as4[0], y = as4[1];
#pragma unroll
    for (int p = 0; p < 8; ++p)
      gload_lds16(bimg + p * 4096 + tid * 16, smem + 8192 + p * 4096 + tid * 16);
    bf16x8 v;
    v[0] = (__bf16)x.x; v[1] = (__bf16)x.y; v[2] = (__bf16)x.z; v[3] = (__bf16)x.w;
    v[4] = (__bf16)y.x; v[5] = (__bf16)y.y; v[6] = (__bf16)y.z; v[7] = (__bf16)y.w;
    *(bf16x8*)(smem + a_woff) = v;
  }
  __syncthreads();

  // ---- main loop
  for (int t = 0; t < 32; ++t) {
    const int cur = t & 1;
    char* ab = smem + cur * 4096;
    char* bb = smem + 8192 + cur * 32768;
    float4 an0, an1;
    // issue next-tile stage (B direct-to-LDS, A global->reg)
    if (t < 31) {
      const char* bs = bimg + (size_t)(t + 1) * 32768;
      char* bd = smem + 8192 + (cur ^ 1) * 32768;
#pragma unroll
      for (int p = 0; p < 8; ++p)
        gload_lds16(bs + p * 4096 + tid * 16, bd + p * 4096 + tid * 16);
      const float4* as4 = (const float4*)(asrc + (t + 1) * 32);
      an0 = as4[0]; an1 = as4[1];
    }
    // fragments for tile t
    bf16x8 af[4], bfr[8];
#pragma unroll
    for (int mf = 0; mf < 4; ++mf)
      af[mf] = *(const bf16x8*)(ab + q * 1024 + (mf * 16 + c0) * 16);
#pragma unroll
    for (int nf = 0; nf < 8; ++nf)
      bfr[nf] = *(const bf16x8*)(bb + q * 8192 + (wc * 128 + nf * 16 + c0) * 16);
    __builtin_amdgcn_s_setprio(1);
#pragma unroll
    for (int mf = 0; mf < 4; ++mf)
#pragma unroll
      for (int nf = 0; nf < 8; ++nf)
        acc[mf][nf] = __builtin_amdgcn_mfma_f32_16x16x32_bf16(af[mf], bfr[nf],
                                                              acc[mf][nf], 0, 0, 0);
    __builtin_amdgcn_s_setprio(0);
    // finish A stage for t+1 (cvt + ds_write into alt buffer)
    if (t < 31) {
      bf16x8 v;
      v[0] = (__bf16)an0.x; v[1] = (__bf16)an0.y; v[2] = (__bf16)an0.z; v[3] = (__bf16)an0.w;
      v[4] = (__bf16)an1.x; v[5] = (__bf16)an1.y; v[6] = (__bf16)an1.z; v[7] = (__bf16)an1.w;
      *(bf16x8*)(smem + (cur ^ 1) * 4096 + a_woff) = v;
    }
    __syncthreads();
  }

  // ---- epilogue: C/D layout col = lane&15, row = q*4 + reg
  float av[8];
#pragma unroll
  for (int nf = 0; nf < 8; ++nf) av[nf] = attv[wc * 128 + nf * 16 + c0];

#pragma unroll
  for (int mf = 0; mf < 4; ++mf) {
#pragma unroll
    for (int rg = 0; rg < 4; ++rg) {
      const int rl = mf * 16 + q * 4 + rg;             // local row 0..63
      const int b = rl & 31;                           // r = s*32+b, tile%32==0
      const float* drow = dec_att + b * 512 + wc * 128 + c0;
      float sum = 0.f;
#pragma unroll
      for (int nf = 0; nf < 8; ++nf) {
        float x = acc[mf][nf][rg] + drow[nf * 16];
        float e = __expf(2.f * x);                     // tanh(x) = 1 - 2/(e^{2x}+1)
        float t = 1.f - 2.f / (e + 1.f);
        sum += t * av[nf];
      }
      sum += __shfl_xor(sum, 1, 64);
      sum += __shfl_xor(sum, 2, 64);
      sum += __shfl_xor(sum, 4, 64);
      sum += __shfl_xor(sum, 8, 64);
      if (c0 == 0) part[rl][wc] = sum;
    }
  }
  __syncthreads();
  if (tid < 64) {
    float tot = part[tid][0] + part[tid][1] + part[tid][2] + part[tid][3];
    int r = bm * 64 + tid;
    scores[(r & 31) * 2048 + (r >> 5)] = tot;          // scores[b][s]
  }
}

// ---------------------------------------------------------------------------
// softmax over S=2048 per batch row; 32 blocks x 256 threads
__global__ void softmax_kernel(const float* __restrict__ scores,
                               float* __restrict__ weights) {
  const int b = blockIdx.x;
  const int t = threadIdx.x;
  const float4* row = (const float4*)(scores + b * 2048);
  float4 v0 = row[t];
  float4 v1 = row[t + 256];
  float m = fmaxf(fmaxf(fmaxf(v0.x, v0.y), fmaxf(v0.z, v0.w)),
                  fmaxf(fmaxf(v1.x, v1.y), fmaxf(v1.z, v1.w)));
#pragma unroll
  for (int s = 32; s; s >>= 1) m = fmaxf(m, __shfl_xor(m, s, 64));
  __shared__ float redm[4], reds[4];
  if ((t & 63) == 0) redm[t >> 6] = m;
  __syncthreads();
  m = fmaxf(fmaxf(redm[0], redm[1]), fmaxf(redm[2], redm[3]));
  float4 e0, e1;
  e0.x = __expf(v0.x - m); e0.y = __expf(v0.y - m);
  e0.z = __expf(v0.z - m); e0.w = __expf(v0.w - m);
  e1.x = __expf(v1.x - m); e1.y = __expf(v1.y - m);
  e1.z = __expf(v1.z - m); e1.w = __expf(v1.w - m);
  float s8 = e0.x + e0.y + e0.z + e0.w + e1.x + e1.y + e1.z + e1.w;
#pragma unroll
  for (int s = 32; s; s >>= 1) s8 += __shfl_xor(s8, s, 64);
  if ((t & 63) == 0) reds[t >> 6] = s8;
  __syncthreads();
  float inv = 1.f / (reds[0] + reds[1] + reds[2] + reds[3]);
  e0.x *= inv; e0.y *= inv; e0.z *= inv; e0.w *= inv;
  e1.x *= inv; e1.y *= inv; e1.z *= inv; e1.w *= inv;
  float4* wrow = (float4*)(weights + b * 2048);
  wrow[t] = e0;
  wrow[t + 256] = e1;
}

// ---------------------------------------------------------------------------
// context partials: block = (b, h-chunk of 256, s-chunk of 128)
__global__ void ctx_partial(const float* __restrict__ enc,
                            const float* __restrict__ weights,
                            float* __restrict__ part) {
  const int bid = blockIdx.x;
  const int t = threadIdx.x;
  const int b = bid & 31;
  const int hc = (bid >> 5) & 3;
  const int sc = bid >> 7;          // 0..15
  const int h = hc * 256 + t;
  const float* wrow = weights + b * 2048 + sc * 128;
  const float* ebase = enc + ((size_t)(sc * 128) * 32 + b) * 1024 + h;
  float acc = 0.f;
#pragma unroll 4
  for (int i = 0; i < 128; ++i) acc += wrow[i] * ebase[(size_t)i * 32768];
  part[(size_t)(sc * 32 + b) * 1024 + h] = acc;
}

__global__ void ctx_reduce(const float* __restrict__ part, float* __restrict__ ctx) {
  int idx = blockIdx.x * 256 + threadIdx.x;   // < 32768
  float s = 0.f;
#pragma unroll
  for (int c = 0; c < 16; ++c) s += part[c * 32768 + idx];
  ctx[idx] = s;
}

// ---------------------------------------------------------------------------
extern "C" void kernel_launch(void* const* d_in, const int* in_sizes, int n_in,
                              void* d_out, int out_size, void* d_ws, size_t ws_size,
                              hipStream_t stream) {
  const float* dec_out  = (const float*)d_in[0];   // (32, 1024)
  const float* enc_outs = (const float*)d_in[1];   // (2048, 32, 1024)
  const float* W_enc    = (const float*)d_in[2];   // (512, 1024)
  const float* W_dec    = (const float*)d_in[3];   // (512, 1024)
  const float* att_v    = (const float*)d_in[4];   // (512,)

  float* out = (float*)d_out;
  float* ctx = out;                 // (32,1024) = 32768 floats
  float* weights = out + 32768;     // (32,2048) = 65536 floats

  char* ws = (char*)d_ws;
  float*  ws_dec    = (float*)(ws + WS_DEC_OFF);
  __bf16* ws_wimg   = (__bf16*)(ws + WS_WIMG_OFF);
  float*  ws_scores = (float*)(ws + WS_SCORES_OFF);
  float*  ws_part   = (float*)(ws + WS_PART_OFF);

  dec_att_kernel<<<4096, 256, 0, stream>>>(dec_out, W_dec, ws_dec);
  convert_wenc<<<2048, 256, 0, stream>>>(W_enc, ws_wimg);
  scores_gemm<<<1024, 256, 0, stream>>>(enc_outs, ws_wimg, ws_dec, att_v, ws_scores);
  softmax_kernel<<<32, 256, 0, stream>>>(ws_scores, weights);
  ctx_partial<<<2048, 256, 0, stream>>>(enc_outs, weights, ws_part);
  ctx_reduce<<<128, 256, 0, stream>>>(ws_part, ctx);
}